// Round 1
// baseline (81.633 us; speedup 1.0000x reference)
//
#include <hip/hip_runtime.h>
#include <math.h>

#define HDIM 4096
#define HK 16
#define DK 256
#define VE 512
#define QK 4096
#define VD 8192
#define NCHUNK 16
#define DPC 16           // DK / NCHUNK
#define EPS 1e-6f

// workspace float offsets
#define OFF_Q    0                    // 4096
#define OFF_K    4096                 // 4096
#define OFF_V    8192                 // 8192
#define OFF_AB   16384                // 32 (alpha_lin 16, beta_lin 16)
#define OFF_SIG  16416                // 32 (alpha 16, beta 16)
#define OFF_QH   16448                // 4096
#define OFF_KH   20544                // 4096
#define OFF_VH   24640                // 8192
#define OFF_KQ   32832                // 16
#define OFF_OUT  32848                // 8192
#define OFF_PQ   41040                // NCHUNK*VD = 131072
#define OFF_PK   (41040 + NCHUNK*VD)  // 131072
// total = 303184 floats ~= 1.16 MB

__device__ __forceinline__ float sigmoidf_(float x) { return 1.f / (1.f + __expf(-x)); }
__device__ __forceinline__ float siluf_(float x)    { return x / (1.f + __expf(-x)); }

// ---------------- Kernel 1: fused GEMV over Wq/Wk/Wv/Wa/Wb -------------------
// wave per row, 4 waves/block. 16416 rows total, each row = 4096 fp32.
__global__ __launch_bounds__(256) void k1_gemv_all(
    const float* __restrict__ hvec,
    const float* __restrict__ Wq, const float* __restrict__ Wk,
    const float* __restrict__ Wv, const float* __restrict__ Wa,
    const float* __restrict__ Wb, float* __restrict__ ws) {
  int wave = threadIdx.x >> 6;
  int lane = threadIdx.x & 63;
  int row = blockIdx.x * 4 + wave;
  if (row >= 16416) return;

  const float* W; float* out; int r;
  if (row < 4096)        { W = Wq; r = row;         out = ws + OFF_Q; }
  else if (row < 8192)   { W = Wk; r = row - 4096;  out = ws + OFF_K; }
  else if (row < 16384)  { W = Wv; r = row - 8192;  out = ws + OFF_V; }
  else if (row < 16400)  { W = Wa; r = row - 16384; out = ws + OFF_AB; }
  else                   { W = Wb; r = row - 16400; out = ws + OFF_AB + 16; }

  const float4* row4 = (const float4*)(W + (size_t)r * HDIM);
  const float4* h4   = (const float4*)hvec;
  float acc = 0.f;
#pragma unroll
  for (int j = 0; j < 16; ++j) {
    float4 w = row4[j * 64 + lane];
    float4 hv = h4[j * 64 + lane];
    acc += w.x * hv.x + w.y * hv.y + w.z * hv.z + w.w * hv.w;
  }
#pragma unroll
  for (int off = 32; off; off >>= 1) acc += __shfl_xor(acc, off, 64);
  if (lane == 0) out[r] = acc;
}

// ------------- Kernel 2: conv taps + silu + l2norm + sigmoid + kq ------------
// one block per head, 256 threads.
__global__ __launch_bounds__(256) void k2_conv_norm(
    const float* __restrict__ qcw, const float* __restrict__ kcw,
    const float* __restrict__ vcw,
    const float* __restrict__ qc,  const float* __restrict__ kc,
    const float* __restrict__ vc,  float* __restrict__ ws) {
  int hh = blockIdx.x;        // head 0..15
  int d  = threadIdx.x;       // 0..255
  int i  = hh * DK + d;       // q/k channel

  float q1 = qc[i*3+0]*qcw[i*4+0] + qc[i*3+1]*qcw[i*4+1] + qc[i*3+2]*qcw[i*4+2]
           + ws[OFF_Q + i]*qcw[i*4+3];
  q1 = siluf_(q1);
  float k1 = kc[i*3+0]*kcw[i*4+0] + kc[i*3+1]*kcw[i*4+1] + kc[i*3+2]*kcw[i*4+2]
           + ws[OFF_K + i]*kcw[i*4+3];
  k1 = siluf_(k1);

  // v: two channels per thread
  int iv0 = hh * VE + d, iv1 = iv0 + 256;
  float v0 = vc[iv0*3+0]*vcw[iv0*4+0] + vc[iv0*3+1]*vcw[iv0*4+1] + vc[iv0*3+2]*vcw[iv0*4+2]
           + ws[OFF_V + iv0]*vcw[iv0*4+3];
  float v1 = vc[iv1*3+0]*vcw[iv1*4+0] + vc[iv1*3+1]*vcw[iv1*4+1] + vc[iv1*3+2]*vcw[iv1*4+2]
           + ws[OFF_V + iv1]*vcw[iv1*4+3];
  ws[OFF_VH + iv0] = siluf_(v0);
  ws[OFF_VH + iv1] = siluf_(v1);

  // block-reduce ssq_q, ssq_k, sum q1*k1
  float a = q1 * q1, b = k1 * k1, c = q1 * k1;
#pragma unroll
  for (int off = 32; off; off >>= 1) {
    a += __shfl_xor(a, off, 64);
    b += __shfl_xor(b, off, 64);
    c += __shfl_xor(c, off, 64);
  }
  __shared__ float sA[4], sB[4], sC[4];
  int wave = threadIdx.x >> 6, lane = threadIdx.x & 63;
  if (lane == 0) { sA[wave] = a; sB[wave] = b; sC[wave] = c; }
  __syncthreads();
  float ssq = sA[0] + sA[1] + sA[2] + sA[3];
  float ssk = sB[0] + sB[1] + sB[2] + sB[3];
  float sqk = sC[0] + sC[1] + sC[2] + sC[3];
  float rq = rsqrtf(ssq + EPS), rk = rsqrtf(ssk + EPS);

  ws[OFF_QH + i] = q1 * rq;
  ws[OFF_KH + i] = k1 * rk;
  if (d == 0) ws[OFF_KQ + hh] = sqk * rq * rk;
  if (hh == 0 && d < 32) ws[OFF_SIG + d] = sigmoidf_(ws[OFF_AB + d]);
}

// --------- Kernel 3: state partial sums  Sq/Sk over d-chunks -----------------
// grid 256 = 16 heads x 16 chunks; 512 threads = one per v column.
__global__ __launch_bounds__(512) void k3_state_partial(
    const float* __restrict__ state, float* __restrict__ ws) {
  int hh = blockIdx.x >> 4;
  int c  = blockIdx.x & 15;
  int vv = threadIdx.x;
  int d0 = c * DPC;
  float aq = 0.f, ak = 0.f;
#pragma unroll
  for (int t = 0; t < DPC; ++t) {
    int d = d0 + t;
    float s = state[((size_t)(hh * DK + d)) * VE + vv];
    aq += s * ws[OFF_QH + hh * DK + d];
    ak += s * ws[OFF_KH + hh * DK + d];
  }
  ws[OFF_PQ + c * VD + hh * VE + vv] = aq;
  ws[OFF_PK + c * VD + hh * VE + vv] = ak;
}

// --------- Kernel 4: reduce partials + gated-delta combine -> out ------------
// 16 blocks x 512 threads
__global__ __launch_bounds__(512) void k4_combine(float* __restrict__ ws) {
  int hh = blockIdx.x, vv = threadIdx.x;
  float Sq = 0.f, Sk = 0.f;
#pragma unroll
  for (int c = 0; c < NCHUNK; ++c) {
    Sq += ws[OFF_PQ + c * VD + hh * VE + vv];
    Sk += ws[OFF_PK + c * VD + hh * VE + vv];
  }
  float a  = ws[OFF_SIG + hh];
  float b  = ws[OFF_SIG + 16 + hh];
  float kq = ws[OFF_KQ + hh];
  float vh = ws[OFF_VH + hh * VE + vv];
  // out = a*Sq + b*kq*(vh - a*Sk)
  ws[OFF_OUT + hh * VE + vv] = a * Sq + b * kq * (vh - a * Sk);
}

// --------------- Kernel 5: output GEMV  d_out = Wo @ out ---------------------
// wave per row, 4 waves/block. 4096 rows, each row = 8192 fp32.
__global__ __launch_bounds__(256) void k5_gemv_out(
    const float* __restrict__ Wo, const float* __restrict__ ws,
    float* __restrict__ dout) {
  int wave = threadIdx.x >> 6;
  int lane = threadIdx.x & 63;
  int row = blockIdx.x * 4 + wave;
  const float4* row4 = (const float4*)(Wo + (size_t)row * VD);
  const float4* o4   = (const float4*)(ws + OFF_OUT);
  float acc = 0.f;
#pragma unroll
  for (int j = 0; j < 32; ++j) {
    float4 w = row4[j * 64 + lane];
    float4 o = o4[j * 64 + lane];
    acc += w.x * o.x + w.y * o.y + w.z * o.z + w.w * o.w;
  }
#pragma unroll
  for (int off = 32; off; off >>= 1) acc += __shfl_xor(acc, off, 64);
  if (lane == 0) dout[row] = acc;
}

extern "C" void kernel_launch(void* const* d_in, const int* in_sizes, int n_in,
                              void* d_out, int out_size, void* d_ws, size_t ws_size,
                              hipStream_t stream) {
  const float* hvec = (const float*)d_in[0];
  const float* Wq   = (const float*)d_in[1];
  const float* Wk   = (const float*)d_in[2];
  const float* Wv   = (const float*)d_in[3];
  const float* Wo   = (const float*)d_in[4];
  const float* Wa   = (const float*)d_in[5];
  const float* Wb   = (const float*)d_in[6];
  const float* qcw  = (const float*)d_in[7];
  const float* kcw  = (const float*)d_in[8];
  const float* vcw  = (const float*)d_in[9];
  const float* qc   = (const float*)d_in[10];
  const float* kc   = (const float*)d_in[11];
  const float* vc   = (const float*)d_in[12];
  const float* state= (const float*)d_in[13];
  float* ws  = (float*)d_ws;
  float* out = (float*)d_out;

  k1_gemv_all<<<4104, 256, 0, stream>>>(hvec, Wq, Wk, Wv, Wa, Wb, ws);
  k2_conv_norm<<<16, 256, 0, stream>>>(qcw, kcw, vcw, qc, kc, vc, ws);
  k3_state_partial<<<256, 512, 0, stream>>>(state, ws);
  k4_combine<<<16, 512, 0, stream>>>(ws);
  k5_gemv_out<<<1024, 256, 0, stream>>>(Wo, ws, out);
}